// Round 1
// 812.067 us; speedup vs baseline: 1.0564x; 1.0564x over previous
//
#include <hip/hip_runtime.h>
#include <cmath>

#define LSEQ 2048
#define NBATCH 8

typedef __attribute__((ext_vector_type(8))) short short8;
typedef __attribute__((ext_vector_type(4))) float f32x4;

__device__ __forceinline__ float silu_f(float x) { return x / (1.0f + __expf(-x)); }
__device__ __forceinline__ float softplus_f(float x) {
    return fmaxf(x, 0.0f) + log1pf(__expf(-fabsf(x)));
}
__device__ __forceinline__ unsigned short f2bf(float f) {   // RNE fp32->bf16
    unsigned int u = __float_as_uint(f);
    u += 0x7FFFu + ((u >> 16) & 1u);
    return (unsigned short)(u >> 16);
}
__device__ __forceinline__ float bf2f(unsigned short h) {
    return __uint_as_float(((unsigned int)h) << 16);
}
__device__ __forceinline__ void gload_lds16(const void* g, void* l) {
    __builtin_amdgcn_global_load_lds((const __attribute__((address_space(1))) void*)g,
                                     (__attribute__((address_space(3))) void*)l, 16, 0, 0);
}

#if defined(__has_builtin)
#if __has_builtin(__builtin_amdgcn_exp2f)
#define EXP2F(x) __builtin_amdgcn_exp2f(x)
#endif
#endif
#ifndef EXP2F
#define EXP2F(x) __expf((x) * 0.69314718055994531f)
#endif

// fwd/bwd operand pairs; blockIdx.z selects direction
struct GemmPair {
    const unsigned short* A[2];
    const unsigned short* A2[2];   // DUAL second A (second K-half, row-reversed)
    const unsigned short* W[2];
    const float* bias[2];
    void* C[2];
    unsigned short* aux[2];
};

// ---------------------------------------------------------------------------
// bf16 MFMA GEMM (NT), r4-proven config: BK=32, scalar epilogue.
// WGM x WGN waves; each wave 64x64 via 4x4 mfma_f32_16x16x32_bf16.
// blockIdx.x = m-tile (gridDim.x % 8 == 0 keeps same-A blocks on one XCD).
// OMODE: 0=f32, 1=bf16. DK: k0>=DK reads A2 (stride lda) at row^2047.
// XTRA: bf16 copy of cols<32 to aux.
// ---------------------------------------------------------------------------
template<int WGM, int WGN, int OMODE, int DK, int XTRA>
__global__ __launch_bounds__(WGM* WGN * 64) void gemm_mfma(GemmPair gp, int lda, int ldw,
                                                           int ldc, int K)
{
    constexpr int NW = WGM * WGN;
    constexpr int TM = WGM * 64, TN = WGN * 64;
    __shared__ unsigned short As[TM * 32];
    __shared__ unsigned short Bs[TN * 32];
    const int dir = blockIdx.z;
    const unsigned short* A  = gp.A[dir];
    const unsigned short* A2 = gp.A2[dir];
    const unsigned short* W  = gp.W[dir];
    const float* bias        = gp.bias[dir];
    void* Cout               = gp.C[dir];
    unsigned short* aux      = gp.aux[dir];

    const int tid = threadIdx.x;
    const int wave = tid >> 6, lane = tid & 63;
    const int wm = wave / WGN, wn = wave % WGN;
    const int m0 = blockIdx.x * TM, n0 = blockIdx.y * TN;
    const int l15 = lane & 15, l4 = lane >> 4;
    const int srow = lane >> 2, schunk = (lane & 3) * 8;

    f32x4 acc[4][4] = {};

    for (int k0 = 0; k0 < K; k0 += 32) {
        __syncthreads();
        for (int s = wave; s < TM / 16; s += NW) {
            const int gr = m0 + s * 16 + srow;
            const unsigned short* g;
            if (DK != 0 && k0 >= DK)
                g = A2 + (size_t)(gr ^ (LSEQ - 1)) * lda + (k0 - DK) + schunk;
            else
                g = A + (size_t)gr * lda + k0 + schunk;
            gload_lds16(g, (char*)As + (size_t)s * 1024);
        }
        for (int s = wave; s < TN / 16; s += NW) {
            const int gr = n0 + s * 16 + srow;
            const unsigned short* g = W + (size_t)gr * ldw + k0 + schunk;
            gload_lds16(g, (char*)Bs + (size_t)s * 1024);
        }
        __syncthreads();
        short8 af[4], bfr[4];
#pragma unroll
        for (int mi = 0; mi < 4; ++mi)
            af[mi] = *(const short8*)&As[(wm * 64 + mi * 16 + l15) * 32 + l4 * 8];
#pragma unroll
        for (int ni = 0; ni < 4; ++ni)
            bfr[ni] = *(const short8*)&Bs[(wn * 64 + ni * 16 + l15) * 32 + l4 * 8];
#pragma unroll
        for (int mi = 0; mi < 4; ++mi)
#pragma unroll
            for (int ni = 0; ni < 4; ++ni)
                acc[mi][ni] = __builtin_amdgcn_mfma_f32_16x16x32_bf16(af[mi], bfr[ni], acc[mi][ni], 0, 0, 0);
    }

#pragma unroll
    for (int mi = 0; mi < 4; ++mi)
#pragma unroll
        for (int ni = 0; ni < 4; ++ni)
#pragma unroll
            for (int r = 0; r < 4; ++r) {
                const int row = m0 + wm * 64 + mi * 16 + l4 * 4 + r;
                const int col = n0 + wn * 64 + ni * 16 + l15;
                float v = acc[mi][ni][r];
                if (bias) v += bias[col];
                if (OMODE & 1) ((unsigned short*)Cout)[(size_t)row * ldc + col] = f2bf(v);
                else           ((float*)Cout)[(size_t)row * ldc + col] = v;
                if (XTRA) { if (col < 32) aux[(size_t)row * 32 + col] = f2bf(v); }
            }
}

// ---------------------------------------------------------------------------
// Combined weight for fused out-proj+final (proven r7: identical absmax):
// Wcomb[n, d + dir*1024] = sum_j lin_w[n, j + dir*512] * ow_dir[j, d]  (bf16)
// ---------------------------------------------------------------------------
__global__ __launch_bounds__(256) void combine_k(
    const float* __restrict__ lin_w, const float* __restrict__ owf,
    const float* __restrict__ owb, unsigned short* __restrict__ Wcomb)
{
    const int dir = blockIdx.z;
    const float* ow = dir ? owb : owf;
    const int lane = threadIdx.x & 63;
    const int wave = threadIdx.x >> 6;
    const int n = blockIdx.y * 4 + wave;          // 0..511
    const int d = blockIdx.x * 256 + lane * 4;    // 0..1023
    float4 acc = {0.f, 0.f, 0.f, 0.f};
    const float* lrow = lin_w + (size_t)n * 1024 + dir * 512;
    for (int j = 0; j < 512; ++j) {
        const float s = lrow[j];
        const float4 v = *(const float4*)&ow[(size_t)j * 1024 + d];
        acc.x = fmaf(s, v.x, acc.x); acc.y = fmaf(s, v.y, acc.y);
        acc.z = fmaf(s, v.z, acc.z); acc.w = fmaf(s, v.w, acc.w);
    }
    ushort4 o;
    o.x = f2bf(acc.x); o.y = f2bf(acc.y); o.z = f2bf(acc.z); o.w = f2bf(acc.w);
    *(ushort4*)&Wcomb[(size_t)n * 2048 + dir * 1024 + d] = o;
}

// ---------------------------------------------------------------------------
// fp32 -> bf16 conversion: 6 weight segments, one launch.
// ---------------------------------------------------------------------------
struct CvtArgs { const float* s[6]; unsigned short* d[6]; int n[6]; };
__global__ __launch_bounds__(256) void cvt_k(CvtArgs a)
{
    const int sid = blockIdx.y;
    const float* s = a.s[sid];
    unsigned short* d = a.d[sid];
    const int n4 = a.n[sid] >> 2;
    for (int i = blockIdx.x * 256 + threadIdx.x; i < n4; i += gridDim.x * 256) {
        const float4 v = ((const float4*)s)[i];
        ushort4 o; o.x = f2bf(v.x); o.y = f2bf(v.y); o.z = f2bf(v.z); o.w = f2bf(v.w);
        ((ushort4*)d)[i] = o;
    }
}
__global__ __launch_bounds__(256) void cvtx_k(const float* __restrict__ s,
                                              unsigned short* __restrict__ d, int n4)
{
    for (int i = blockIdx.x * 256 + threadIdx.x; i < n4; i += gridDim.x * 256) {
        const float4 v = ((const float4*)s)[i];
        ushort4 o; o.x = f2bf(v.x); o.y = f2bf(v.y); o.z = f2bf(v.z); o.w = f2bf(v.w);
        ((ushort4*)d)[i] = o;
    }
}

// ---------------------------------------------------------------------------
// Causal depthwise conv(4) + bias + SiLU, both dirs; bf16 in (xz cols 0..1023,
// ld 2048), bf16 out. Backward dir indexes reversed rows.
// ---------------------------------------------------------------------------
__global__ __launch_bounds__(256) void conv_silu_k(
    const unsigned short* __restrict__ xz_f, const float* __restrict__ cw_f,
    const float* __restrict__ cb_f, unsigned short* __restrict__ xi_f,
    const unsigned short* __restrict__ xz_b, const float* __restrict__ cw_b,
    const float* __restrict__ cb_b, unsigned short* __restrict__ xi_b)
{
    const int dir = blockIdx.y;
    const unsigned short* xz = dir ? xz_b : xz_f;
    const float* cw = dir ? cw_b : cw_f;
    const float* cb = dir ? cb_b : cb_f;
    unsigned short* xi = dir ? xi_b : xi_f;

    const int bt = blockIdx.x;
    const int b = bt >> 11;
    const int t = bt & (LSEQ - 1);
    const int d = threadIdx.x << 2;

    float w[4][4];
#pragma unroll
    for (int i = 0; i < 4; ++i) {
        const float4 wr = *(const float4*)&cw[(d + i) * 4];
        w[i][0] = wr.x; w[i][1] = wr.y; w[i][2] = wr.z; w[i][3] = wr.w;
    }
    float4 acc = *(const float4*)&cb[d];
#pragma unroll
    for (int k = 0; k < 4; ++k) {
        const int row = dir ? (LSEQ - 1 - t) + 3 - k : t - 3 + k;
        if ((unsigned)row < (unsigned)LSEQ) {
            const ushort4 v = *(const ushort4*)&xz[(size_t)(b * LSEQ + row) * 2048 + d];
            acc.x += w[0][k] * bf2f(v.x); acc.y += w[1][k] * bf2f(v.y);
            acc.z += w[2][k] * bf2f(v.z); acc.w += w[3][k] * bf2f(v.w);
        }
    }
    ushort4 st;
    st.x = f2bf(silu_f(acc.x)); st.y = f2bf(silu_f(acc.y));
    st.z = f2bf(silu_f(acc.z)); st.w = f2bf(silu_f(acc.w));
    *(ushort4*)&xi[(size_t)(b * LSEQ + t) * 1024 + d] = st;
}

// ---------------------------------------------------------------------------
// Selective scan, 2-states-per-thread version.
// Block = 256 threads = 32 channels (di=tid>>3) x 8 state-pairs (np=tid&7);
// thread owns states n=np and n=np+8. Per 64-t chunk:
//   stage xi/B/C (B,C as {n,n+8} interleaved pairs),
//   dt via one MFMA per wave per 16-ch half (+softplus), dtx = dt*xi staged,
//   inner loop: 2 fma-chains + 3-step 8-lane DPP reduce,
//   epilogue: y + xi*Dp gated by silu(z), bf16 in place over xi.
// ---------------------------------------------------------------------------
__device__ __forceinline__ float row_sum8(float x) {
    x += __int_as_float(__builtin_amdgcn_update_dpp(0, __float_as_int(x), 0xB1, 0xF, 0xF, false));  // quad xor1
    x += __int_as_float(__builtin_amdgcn_update_dpp(0, __float_as_int(x), 0x4E, 0xF, 0xF, false));  // quad xor2
    x += __int_as_float(__builtin_amdgcn_update_dpp(0, __float_as_int(x), 0x141, 0xF, 0xF, false)); // row_half_mirror
    return x;
}

struct ScanPair {
    const unsigned short* dblh[2];   // (rows x 32) bf16
    const unsigned short* dtw[2];    // (1024 x 32) bf16
    const float* dtb[2];             // (1024) f32
    unsigned short* xiy[2];          // (rows x 1024) bf16, in/out
    const float* dbl[2];             // (rows x 64) f32, B/C in cols 32..63
    const unsigned short* xz[2];     // (rows x 2048) bf16, z in cols 1024+
    const float* Al[2];
    const float* Dp[2];
};

__global__ __launch_bounds__(256) void scan_k(ScanPair sp)
{
    __shared__ float sdt[32][68], sdtx[32][68], sxi[32][68];
    __shared__ float sB2[8][140], sC2[8][140];   // [np][t*2+half]: {B_np, B_np+8}
    __shared__ float sy[64][36];                 // [t][ch]

    const int dir = blockIdx.z;
    const unsigned short* dblh = sp.dblh[dir];
    const unsigned short* dtw  = sp.dtw[dir];
    const float* dtb           = sp.dtb[dir];
    unsigned short* xiy        = sp.xiy[dir];
    const float* dbl           = sp.dbl[dir];
    const unsigned short* zz   = sp.xz[dir];
    const float* Al            = sp.Al[dir];
    const float* Dpp           = sp.Dp[dir];

    const int b = blockIdx.y, d0 = blockIdx.x << 5;
    const int tid = threadIdx.x;
    const int wave = tid >> 6, lane = tid & 63;
    const int l15 = lane & 15, l4 = lane >> 4;
    const int di = tid >> 3, np = tid & 7;     // inner-loop mapping
    const int lr = tid >> 2, lc = tid & 3;     // stage/epilogue mapping

    // A constants pre-scaled by log2(e) so exp2 needs no extra mul
    const float A0L = -expf(Al[(d0 + di) * 16 + np]) * 1.4426950408889634f;
    const float A1L = -expf(Al[(d0 + di) * 16 + np + 8]) * 1.4426950408889634f;

    // dt MFMA B-fragments: rows = the block's 32 channels (two 16-ch halves)
    const short8 dtwf0 = *(const short8*)&dtw[(size_t)(d0 + l15) * 32 + l4 * 8];
    const short8 dtwf1 = *(const short8*)&dtw[(size_t)(d0 + 16 + l15) * 32 + l4 * 8];
    const float dtb0 = dtb[d0 + l15], dtb1 = dtb[d0 + 16 + l15];

    float dpv[8];
#pragma unroll
    for (int i = 0; i < 8; ++i) dpv[i] = Dpp[d0 + lc * 8 + i];

    ushort4 pxi0, pxi1;
    float4 pB, pC;
    short8 pA;
    auto issue_loads = [&](int c) {
        const size_t r = (size_t)b * LSEQ + c * 64 + lr;
        pxi0 = *(const ushort4*)&xiy[r * 1024 + d0 + lc * 8];
        pxi1 = *(const ushort4*)&xiy[r * 1024 + d0 + lc * 8 + 4];
        pB   = *(const float4*)&dbl[r * 64 + 32 + lc * 4];
        pC   = *(const float4*)&dbl[r * 64 + 48 + lc * 4];
        // dt MFMA A-fragment: rows = this wave's 16 timesteps of the chunk
        pA   = *(const short8*)&dblh[(size_t)(b * LSEQ + c * 64 + wave * 16 + l15) * 32 + l4 * 8];
    };
    issue_loads(0);

    float h0 = 0.0f, h1 = 0.0f;
    for (int c = 0; c < LSEQ / 64; ++c) {
        const int t0 = c * 64;
        __syncthreads();
        // ---- stage xi (f32, [ch][t]) and B/C pairs ----
        sxi[lc * 8 + 0][lr] = bf2f(pxi0.x);
        sxi[lc * 8 + 1][lr] = bf2f(pxi0.y);
        sxi[lc * 8 + 2][lr] = bf2f(pxi0.z);
        sxi[lc * 8 + 3][lr] = bf2f(pxi0.w);
        sxi[lc * 8 + 4][lr] = bf2f(pxi1.x);
        sxi[lc * 8 + 5][lr] = bf2f(pxi1.y);
        sxi[lc * 8 + 6][lr] = bf2f(pxi1.z);
        sxi[lc * 8 + 7][lr] = bf2f(pxi1.w);
        {
            const float bv[4] = {pB.x, pB.y, pB.z, pB.w};
            const float cv[4] = {pC.x, pC.y, pC.z, pC.w};
#pragma unroll
            for (int i = 0; i < 4; ++i) {
                const int n = lc * 4 + i;
                sB2[n & 7][lr * 2 + (n >> 3)] = bv[i];
                sC2[n & 7][lr * 2 + (n >> 3)] = cv[i];
            }
        }
        __syncthreads();
        // ---- dt phase: MFMA -> softplus -> sdt, and dtx = dt*xi -> sdtx ----
        {
            f32x4 z4 = {0.f, 0.f, 0.f, 0.f};
            f32x4 dacc0 = __builtin_amdgcn_mfma_f32_16x16x32_bf16(pA, dtwf0, z4, 0, 0, 0);
            f32x4 dacc1 = __builtin_amdgcn_mfma_f32_16x16x32_bf16(pA, dtwf1, z4, 0, 0, 0);
            const int tq = wave * 16 + l4 * 4;
            const float4 xi0 = *(const float4*)&sxi[l15][tq];
            const float4 xi1 = *(const float4*)&sxi[16 + l15][tq];
            float4 dv0, dv1, dx0, dx1;
            dv0.x = softplus_f(dacc0[0] + dtb0); dv0.y = softplus_f(dacc0[1] + dtb0);
            dv0.z = softplus_f(dacc0[2] + dtb0); dv0.w = softplus_f(dacc0[3] + dtb0);
            dv1.x = softplus_f(dacc1[0] + dtb1); dv1.y = softplus_f(dacc1[1] + dtb1);
            dv1.z = softplus_f(dacc1[2] + dtb1); dv1.w = softplus_f(dacc1[3] + dtb1);
            dx0.x = dv0.x * xi0.x; dx0.y = dv0.y * xi0.y;
            dx0.z = dv0.z * xi0.z; dx0.w = dv0.w * xi0.w;
            dx1.x = dv1.x * xi1.x; dx1.y = dv1.y * xi1.y;
            dx1.z = dv1.z * xi1.z; dx1.w = dv1.w * xi1.w;
            *(float4*)&sdt[l15][tq]       = dv0;
            *(float4*)&sdt[16 + l15][tq]  = dv1;
            *(float4*)&sdtx[l15][tq]      = dx0;
            *(float4*)&sdtx[16 + l15][tq] = dx1;
        }
        if (c + 1 < LSEQ / 64) issue_loads(c + 1);
        ushort4 pz0, pz1;
        {
            const int tz = dir ? (LSEQ - 1 - (t0 + lr)) : (t0 + lr);
            pz0 = *(const ushort4*)&zz[((size_t)b * LSEQ + tz) * 2048 + 1024 + d0 + lc * 8];
            pz1 = *(const ushort4*)&zz[((size_t)b * LSEQ + tz) * 2048 + 1024 + d0 + lc * 8 + 4];
        }
        __syncthreads();
        // ---- inner scan: 64 timesteps, 2 states per thread ----
#pragma unroll 4
        for (int tt = 0; tt < 64; tt += 4) {
            const float4 d4 = *(const float4*)&sdt[di][tt];
            const float4 u4 = *(const float4*)&sdtx[di][tt];
            const float4 bA = *(const float4*)&sB2[np][tt * 2];
            const float4 bB = *(const float4*)&sB2[np][tt * 2 + 4];
            const float4 cA = *(const float4*)&sC2[np][tt * 2];
            const float4 cB = *(const float4*)&sC2[np][tt * 2 + 4];
            {
                h0 = fmaf(EXP2F(d4.x * A0L), h0, u4.x * bA.x);
                h1 = fmaf(EXP2F(d4.x * A1L), h1, u4.x * bA.y);
                const float pp = row_sum8(fmaf(h1, cA.y, h0 * cA.x));
                if (np == 0) sy[tt + 0][di] = pp;
            }
            {
                h0 = fmaf(EXP2F(d4.y * A0L), h0, u4.y * bA.z);
                h1 = fmaf(EXP2F(d4.y * A1L), h1, u4.y * bA.w);
                const float pp = row_sum8(fmaf(h1, cA.w, h0 * cA.z));
                if (np == 0) sy[tt + 1][di] = pp;
            }
            {
                h0 = fmaf(EXP2F(d4.z * A0L), h0, u4.z * bB.x);
                h1 = fmaf(EXP2F(d4.z * A1L), h1, u4.z * bB.y);
                const float pp = row_sum8(fmaf(h1, cB.y, h0 * cB.x));
                if (np == 0) sy[tt + 2][di] = pp;
            }
            {
                h0 = fmaf(EXP2F(d4.w * A0L), h0, u4.w * bB.z);
                h1 = fmaf(EXP2F(d4.w * A1L), h1, u4.w * bB.w);
                const float pp = row_sum8(fmaf(h1, cB.w, h0 * cB.z));
                if (np == 0) sy[tt + 3][di] = pp;
            }
        }
        __syncthreads();
        // ---- epilogue: y + xi*Dp, gate by silu(z), store bf16 ----
        {
            const size_t r = (size_t)b * LSEQ + t0 + lr;
            const float4 y0 = *(const float4*)&sy[lr][lc * 8];
            const float4 y1 = *(const float4*)&sy[lr][lc * 8 + 4];
            float xiv[8];
#pragma unroll
            for (int i = 0; i < 8; ++i) xiv[i] = sxi[lc * 8 + i][lr];
            ushort4 s0, s1;
            s0.x = f2bf(fmaf(xiv[0], dpv[0], y0.x) * silu_f(bf2f(pz0.x)));
            s0.y = f2bf(fmaf(xiv[1], dpv[1], y0.y) * silu_f(bf2f(pz0.y)));
            s0.z = f2bf(fmaf(xiv[2], dpv[2], y0.z) * silu_f(bf2f(pz0.z)));
            s0.w = f2bf(fmaf(xiv[3], dpv[3], y0.w) * silu_f(bf2f(pz0.w)));
            s1.x = f2bf(fmaf(xiv[4], dpv[4], y1.x) * silu_f(bf2f(pz1.x)));
            s1.y = f2bf(fmaf(xiv[5], dpv[5], y1.y) * silu_f(bf2f(pz1.y)));
            s1.z = f2bf(fmaf(xiv[6], dpv[6], y1.z) * silu_f(bf2f(pz1.z)));
            s1.w = f2bf(fmaf(xiv[7], dpv[7], y1.w) * silu_f(bf2f(pz1.w)));
            *(ushort4*)&xiy[r * 1024 + d0 + lc * 8] = s0;
            *(ushort4*)&xiy[r * 1024 + d0 + lc * 8 + 4] = s1;
        }
    }
}

// ---------------------------------------------------------------------------
extern "C" void kernel_launch(void* const* d_in, const int* in_sizes, int n_in,
                              void* d_out, int out_size, void* d_ws, size_t ws_size,
                              hipStream_t stream)
{
    const float* x      = (const float*)d_in[0];
    const float* f_in_w = (const float*)d_in[1];
    const float* f_cw   = (const float*)d_in[2];
    const float* f_cb   = (const float*)d_in[3];
    const float* f_xp   = (const float*)d_in[4];
    const float* f_dtw  = (const float*)d_in[5];
    const float* f_dtb  = (const float*)d_in[6];
    const float* f_Al   = (const float*)d_in[7];
    const float* f_Dp   = (const float*)d_in[8];
    const float* f_ow   = (const float*)d_in[9];
    const float* b_in_w = (const float*)d_in[10];
    const float* b_cw   = (const float*)d_in[11];
    const float* b_cb   = (const float*)d_in[12];
    const float* b_xp   = (const float*)d_in[13];
    const float* b_dtw  = (const float*)d_in[14];
    const float* b_dtb  = (const float*)d_in[15];
    const float* b_Al   = (const float*)d_in[16];
    const float* b_Dp   = (const float*)d_in[17];
    const float* b_ow   = (const float*)d_in[18];
    const float* lin_w  = (const float*)d_in[19];
    const float* lin_b  = (const float*)d_in[20];
    float* out = (float*)d_out;

    char* p = (char*)d_ws;
    auto take = [&](size_t bytes) -> char* {
        char* r = p; p += (bytes + 255) & ~(size_t)255; return r;
    };

    // persistent bf16 weights
    unsigned short* wif  = (unsigned short*)take((size_t)2048 * 512 * 2);
    unsigned short* wib  = (unsigned short*)take((size_t)2048 * 512 * 2);
    unsigned short* wxf  = (unsigned short*)take((size_t)64 * 1024 * 2);
    unsigned short* wxb  = (unsigned short*)take((size_t)64 * 1024 * 2);
    unsigned short* wdtf = (unsigned short*)take((size_t)1024 * 32 * 2);
    unsigned short* wdtb = (unsigned short*)take((size_t)1024 * 32 * 2);
    unsigned short* wcmb = (unsigned short*)take((size_t)512 * 2048 * 2);

    const size_t used = (size_t)(p - (char*)d_ws);
    // per-row bytes: xbf 1024 + per dir (xz 4096 + xiy 2048 + dbl 256 + dblh 64)
    const size_t perRow = 1024 + 2 * (4096 + 2048 + 256 + 64);
    int G = 1;
    for (int g = 8; g >= 1; g >>= 1) {
        const size_t need = used + (size_t)g * LSEQ * perRow + 16384;
        if (need <= ws_size || g == 1) { G = g; break; }
    }

    CvtArgs ca;
    ca.s[0] = f_in_w; ca.d[0] = wif;  ca.n[0] = 2048 * 512;
    ca.s[1] = b_in_w; ca.d[1] = wib;  ca.n[1] = 2048 * 512;
    ca.s[2] = f_xp;   ca.d[2] = wxf;  ca.n[2] = 64 * 1024;
    ca.s[3] = b_xp;   ca.d[3] = wxb;  ca.n[3] = 64 * 1024;
    ca.s[4] = f_dtw;  ca.d[4] = wdtf; ca.n[4] = 1024 * 32;
    ca.s[5] = b_dtw;  ca.d[5] = wdtb; ca.n[5] = 1024 * 32;
    cvt_k<<<dim3(128, 6), 256, 0, stream>>>(ca);

    // combined (lin_w @ out_w) weight, bf16, (512 x 2048) — proven r7
    combine_k<<<dim3(4, 128, 2), 256, 0, stream>>>(lin_w, f_ow, b_ow, wcmb);

    char* pg0 = p;
    for (int g0 = 0; g0 < NBATCH; g0 += G) {
        const int Mg = G * LSEQ;
        p = pg0;
        unsigned short* xbf   = (unsigned short*)take((size_t)Mg * 512 * 2);
        unsigned short* xz_f  = (unsigned short*)take((size_t)Mg * 2048 * 2);
        unsigned short* xz_b  = (unsigned short*)take((size_t)Mg * 2048 * 2);
        unsigned short* xiy_f = (unsigned short*)take((size_t)Mg * 1024 * 2);
        unsigned short* xiy_b = (unsigned short*)take((size_t)Mg * 1024 * 2);
        float* dbl_f          = (float*)take((size_t)Mg * 64 * 4);
        float* dbl_b          = (float*)take((size_t)Mg * 64 * 4);
        unsigned short* dblh_f= (unsigned short*)take((size_t)Mg * 32 * 2);
        unsigned short* dblh_b= (unsigned short*)take((size_t)Mg * 32 * 2);

        const float* xg = x + (size_t)g0 * LSEQ * 512;
        float* outg = out + (size_t)g0 * LSEQ * 512;

        cvtx_k<<<dim3(512), 256, 0, stream>>>(xg, xbf, Mg * 512 / 4);

        GemmPair g1 = {};   // in-proj: xz = x @ in_w^T (N=2048), bf16 out
        g1.A[0] = xbf; g1.A[1] = xbf; g1.W[0] = wif; g1.W[1] = wib;
        g1.C[0] = xz_f; g1.C[1] = xz_b;
        gemm_mfma<2,2,1,0,0><<<dim3(Mg/128, 16, 2), 256, 0, stream>>>(g1, 512, 512, 2048, 512);

        conv_silu_k<<<dim3(Mg, 2), 256, 0, stream>>>(xz_f, f_cw, f_cb, xiy_f,
                                                     xz_b, b_cw, b_cb, xiy_b);

        GemmPair g2 = {};   // x-proj: dbl f32 (ldc 64) + bf16 cols<32 (dblh)
        g2.A[0] = xiy_f; g2.A[1] = xiy_b; g2.W[0] = wxf; g2.W[1] = wxb;
        g2.C[0] = dbl_f; g2.C[1] = dbl_b; g2.aux[0] = dblh_f; g2.aux[1] = dblh_b;
        gemm_mfma<4,1,0,0,1><<<dim3(Mg/256, 1, 2), 256, 0, stream>>>(g2, 1024, 1024, 64, 1024);

        ScanPair spp = {};  // scan: 32 ch x 8 state-pairs per block
        spp.dblh[0] = dblh_f; spp.dblh[1] = dblh_b;
        spp.dtw[0] = wdtf;    spp.dtw[1] = wdtb;
        spp.dtb[0] = f_dtb;   spp.dtb[1] = b_dtb;
        spp.xiy[0] = xiy_f;   spp.xiy[1] = xiy_b;
        spp.dbl[0] = dbl_f;   spp.dbl[1] = dbl_b;
        spp.xz[0] = xz_f;     spp.xz[1] = xz_b;
        spp.Al[0] = f_Al;     spp.Al[1] = b_Al;
        spp.Dp[0] = f_Dp;     spp.Dp[1] = b_Dp;
        scan_k<<<dim3(32, G, 2), 256, 0, stream>>>(spp);

        // fused out-proj+final: out = [y_f | rev(y_b)] @ Wcomb^T + lin_b (K=2048)
        GemmPair g5 = {};
        g5.A[0] = xiy_f; g5.A2[0] = xiy_b; g5.W[0] = wcmb;
        g5.bias[0] = lin_b; g5.C[0] = outg;
        gemm_mfma<2,2,0,1024,0><<<dim3(Mg/128, 4, 1), 256, 0, stream>>>(g5, 1024, 2048, 512, 2048);
    }
}

// Round 2
// 736.861 us; speedup vs baseline: 1.1642x; 1.1021x over previous
//
#include <hip/hip_runtime.h>
#include <cmath>

#define LSEQ 2048
#define NBATCH 8

typedef __attribute__((ext_vector_type(8))) short short8;
typedef __attribute__((ext_vector_type(4))) float f32x4;

__device__ __forceinline__ float silu_f(float x) {
    return x * __builtin_amdgcn_rcpf(1.0f + __expf(-x));
}
__device__ __forceinline__ float softplus_f(float x) {
    return fmaxf(x, 0.0f) + __logf(1.0f + __expf(-fabsf(x)));
}
__device__ __forceinline__ unsigned short f2bf(float f) {   // RNE fp32->bf16
    unsigned int u = __float_as_uint(f);
    u += 0x7FFFu + ((u >> 16) & 1u);
    return (unsigned short)(u >> 16);
}
__device__ __forceinline__ float bf2f(unsigned short h) {
    return __uint_as_float(((unsigned int)h) << 16);
}
__device__ __forceinline__ void gload_lds16(const void* g, void* l) {
    __builtin_amdgcn_global_load_lds((const __attribute__((address_space(1))) void*)g,
                                     (__attribute__((address_space(3))) void*)l, 16, 0, 0);
}

#if defined(__has_builtin)
#if __has_builtin(__builtin_amdgcn_exp2f)
#define EXP2F(x) __builtin_amdgcn_exp2f(x)
#endif
#endif
#ifndef EXP2F
#define EXP2F(x) __expf((x) * 0.69314718055994531f)
#endif

// fwd/bwd operand pairs; blockIdx.z selects direction
struct GemmPair {
    const unsigned short* A[2];
    const unsigned short* A2[2];   // DUAL second A (second K-half, row-reversed)
    const unsigned short* W[2];
    const float* bias[2];
    void* C[2];
    unsigned short* aux[2];
};

// ---------------------------------------------------------------------------
// bf16 MFMA GEMM (NT), r4-proven config: BK=32, scalar epilogue.
// ---------------------------------------------------------------------------
template<int WGM, int WGN, int OMODE, int DK, int XTRA>
__global__ __launch_bounds__(WGM* WGN * 64) void gemm_mfma(GemmPair gp, int lda, int ldw,
                                                           int ldc, int K)
{
    constexpr int NW = WGM * WGN;
    constexpr int TM = WGM * 64, TN = WGN * 64;
    __shared__ unsigned short As[TM * 32];
    __shared__ unsigned short Bs[TN * 32];
    const int dir = blockIdx.z;
    const unsigned short* A  = gp.A[dir];
    const unsigned short* A2 = gp.A2[dir];
    const unsigned short* W  = gp.W[dir];
    const float* bias        = gp.bias[dir];
    void* Cout               = gp.C[dir];
    unsigned short* aux      = gp.aux[dir];

    const int tid = threadIdx.x;
    const int wave = tid >> 6, lane = tid & 63;
    const int wm = wave / WGN, wn = wave % WGN;
    const int m0 = blockIdx.x * TM, n0 = blockIdx.y * TN;
    const int l15 = lane & 15, l4 = lane >> 4;
    const int srow = lane >> 2, schunk = (lane & 3) * 8;

    f32x4 acc[4][4] = {};

    for (int k0 = 0; k0 < K; k0 += 32) {
        __syncthreads();
        for (int s = wave; s < TM / 16; s += NW) {
            const int gr = m0 + s * 16 + srow;
            const unsigned short* g;
            if (DK != 0 && k0 >= DK)
                g = A2 + (size_t)(gr ^ (LSEQ - 1)) * lda + (k0 - DK) + schunk;
            else
                g = A + (size_t)gr * lda + k0 + schunk;
            gload_lds16(g, (char*)As + (size_t)s * 1024);
        }
        for (int s = wave; s < TN / 16; s += NW) {
            const int gr = n0 + s * 16 + srow;
            const unsigned short* g = W + (size_t)gr * ldw + k0 + schunk;
            gload_lds16(g, (char*)Bs + (size_t)s * 1024);
        }
        __syncthreads();
        short8 af[4], bfr[4];
#pragma unroll
        for (int mi = 0; mi < 4; ++mi)
            af[mi] = *(const short8*)&As[(wm * 64 + mi * 16 + l15) * 32 + l4 * 8];
#pragma unroll
        for (int ni = 0; ni < 4; ++ni)
            bfr[ni] = *(const short8*)&Bs[(wn * 64 + ni * 16 + l15) * 32 + l4 * 8];
#pragma unroll
        for (int mi = 0; mi < 4; ++mi)
#pragma unroll
            for (int ni = 0; ni < 4; ++ni)
                acc[mi][ni] = __builtin_amdgcn_mfma_f32_16x16x32_bf16(af[mi], bfr[ni], acc[mi][ni], 0, 0, 0);
    }

#pragma unroll
    for (int mi = 0; mi < 4; ++mi)
#pragma unroll
        for (int ni = 0; ni < 4; ++ni)
#pragma unroll
            for (int r = 0; r < 4; ++r) {
                const int row = m0 + wm * 64 + mi * 16 + l4 * 4 + r;
                const int col = n0 + wn * 64 + ni * 16 + l15;
                float v = acc[mi][ni][r];
                if (bias) v += bias[col];
                if (OMODE & 1) ((unsigned short*)Cout)[(size_t)row * ldc + col] = f2bf(v);
                else           ((float*)Cout)[(size_t)row * ldc + col] = v;
                if (XTRA) { if (col < 32) aux[(size_t)row * 32 + col] = f2bf(v); }
            }
}

// ---------------------------------------------------------------------------
// Combined weight for fused out-proj+final (proven r7: identical absmax):
// ---------------------------------------------------------------------------
__global__ __launch_bounds__(256) void combine_k(
    const float* __restrict__ lin_w, const float* __restrict__ owf,
    const float* __restrict__ owb, unsigned short* __restrict__ Wcomb)
{
    const int dir = blockIdx.z;
    const float* ow = dir ? owb : owf;
    const int lane = threadIdx.x & 63;
    const int wave = threadIdx.x >> 6;
    const int n = blockIdx.y * 4 + wave;          // 0..511
    const int d = blockIdx.x * 256 + lane * 4;    // 0..1023
    float4 acc = {0.f, 0.f, 0.f, 0.f};
    const float* lrow = lin_w + (size_t)n * 1024 + dir * 512;
    for (int j = 0; j < 512; ++j) {
        const float s = lrow[j];
        const float4 v = *(const float4*)&ow[(size_t)j * 1024 + d];
        acc.x = fmaf(s, v.x, acc.x); acc.y = fmaf(s, v.y, acc.y);
        acc.z = fmaf(s, v.z, acc.z); acc.w = fmaf(s, v.w, acc.w);
    }
    ushort4 o;
    o.x = f2bf(acc.x); o.y = f2bf(acc.y); o.z = f2bf(acc.z); o.w = f2bf(acc.w);
    *(ushort4*)&Wcomb[(size_t)n * 2048 + dir * 1024 + d] = o;
}

// ---------------------------------------------------------------------------
// fp32 -> bf16 conversion: 6 weight segments, one launch.
// ---------------------------------------------------------------------------
struct CvtArgs { const float* s[6]; unsigned short* d[6]; int n[6]; };
__global__ __launch_bounds__(256) void cvt_k(CvtArgs a)
{
    const int sid = blockIdx.y;
    const float* s = a.s[sid];
    unsigned short* d = a.d[sid];
    const int n4 = a.n[sid] >> 2;
    for (int i = blockIdx.x * 256 + threadIdx.x; i < n4; i += gridDim.x * 256) {
        const float4 v = ((const float4*)s)[i];
        ushort4 o; o.x = f2bf(v.x); o.y = f2bf(v.y); o.z = f2bf(v.z); o.w = f2bf(v.w);
        ((ushort4*)d)[i] = o;
    }
}
__global__ __launch_bounds__(256) void cvtx_k(const float* __restrict__ s,
                                              unsigned short* __restrict__ d, int n4)
{
    for (int i = blockIdx.x * 256 + threadIdx.x; i < n4; i += gridDim.x * 256) {
        const float4 v = ((const float4*)s)[i];
        ushort4 o; o.x = f2bf(v.x); o.y = f2bf(v.y); o.z = f2bf(v.z); o.w = f2bf(v.w);
        ((ushort4*)d)[i] = o;
    }
}

// ---------------------------------------------------------------------------
// Causal depthwise conv(4) + bias + SiLU, both dirs.
// ---------------------------------------------------------------------------
__global__ __launch_bounds__(256) void conv_silu_k(
    const unsigned short* __restrict__ xz_f, const float* __restrict__ cw_f,
    const float* __restrict__ cb_f, unsigned short* __restrict__ xi_f,
    const unsigned short* __restrict__ xz_b, const float* __restrict__ cw_b,
    const float* __restrict__ cb_b, unsigned short* __restrict__ xi_b)
{
    const int dir = blockIdx.y;
    const unsigned short* xz = dir ? xz_b : xz_f;
    const float* cw = dir ? cw_b : cw_f;
    const float* cb = dir ? cb_b : cb_f;
    unsigned short* xi = dir ? xi_b : xi_f;

    const int bt = blockIdx.x;
    const int b = bt >> 11;
    const int t = bt & (LSEQ - 1);
    const int d = threadIdx.x << 2;

    float w[4][4];
#pragma unroll
    for (int i = 0; i < 4; ++i) {
        const float4 wr = *(const float4*)&cw[(d + i) * 4];
        w[i][0] = wr.x; w[i][1] = wr.y; w[i][2] = wr.z; w[i][3] = wr.w;
    }
    float4 acc = *(const float4*)&cb[d];
#pragma unroll
    for (int k = 0; k < 4; ++k) {
        const int row = dir ? (LSEQ - 1 - t) + 3 - k : t - 3 + k;
        if ((unsigned)row < (unsigned)LSEQ) {
            const ushort4 v = *(const ushort4*)&xz[(size_t)(b * LSEQ + row) * 2048 + d];
            acc.x += w[0][k] * bf2f(v.x); acc.y += w[1][k] * bf2f(v.y);
            acc.z += w[2][k] * bf2f(v.z); acc.w += w[3][k] * bf2f(v.w);
        }
    }
    ushort4 st;
    st.x = f2bf(silu_f(acc.x)); st.y = f2bf(silu_f(acc.y));
    st.z = f2bf(silu_f(acc.z)); st.w = f2bf(silu_f(acc.w));
    *(ushort4*)&xi[(size_t)(b * LSEQ + t) * 1024 + d] = st;
}

// ---------------------------------------------------------------------------
// Selective scan, 2-states-per-thread; round-2 slimming:
//  - __launch_bounds__(256,2): 256-VGPR budget for deep scheduling
//  - sxi transposed [t][ch], double-buffered -> b128 conflict-free staging,
//    top barrier removed (3 barriers/chunk)
//  - row_sum8 with bound_ctrl=1 (fusable v_add_f32_dpp)
//  - per-group float4 sy store (one predicate per 4 timesteps)
//  - softplus via __logf, silu via rcp
// ---------------------------------------------------------------------------
__device__ __forceinline__ float row_sum8(float x) {
    x += __int_as_float(__builtin_amdgcn_update_dpp(0, __float_as_int(x), 0xB1, 0xF, 0xF, true));  // quad xor1
    x += __int_as_float(__builtin_amdgcn_update_dpp(0, __float_as_int(x), 0x4E, 0xF, 0xF, true));  // quad xor2
    x += __int_as_float(__builtin_amdgcn_update_dpp(0, __float_as_int(x), 0x141, 0xF, 0xF, true)); // row_half_mirror
    return x;
}

struct ScanPair {
    const unsigned short* dblh[2];   // (rows x 32) bf16
    const unsigned short* dtw[2];    // (1024 x 32) bf16
    const float* dtb[2];             // (1024) f32
    unsigned short* xiy[2];          // (rows x 1024) bf16, in/out
    const float* dbl[2];             // (rows x 64) f32, B/C in cols 32..63
    const unsigned short* xz[2];     // (rows x 2048) bf16, z in cols 1024+
    const float* Al[2];
    const float* Dp[2];
};

__global__ __launch_bounds__(256, 2) void scan_k(ScanPair sp)
{
    __shared__ float sxi[2][64][36];             // [buf][t][ch]
    __shared__ float sdt[32][68], sdtx[32][68];  // [ch][t]
    __shared__ float sB2[8][140], sC2[8][140];   // [np][t*2+half]: {B_np, B_np+8}
    __shared__ float sy[32][68];                 // [ch][t]

    const int dir = blockIdx.z;
    const unsigned short* dblh = sp.dblh[dir];
    const unsigned short* dtw  = sp.dtw[dir];
    const float* dtb           = sp.dtb[dir];
    unsigned short* xiy        = sp.xiy[dir];
    const float* dbl           = sp.dbl[dir];
    const unsigned short* zz   = sp.xz[dir];
    const float* Al            = sp.Al[dir];
    const float* Dpp           = sp.Dp[dir];

    const int b = blockIdx.y, d0 = blockIdx.x << 5;
    const int tid = threadIdx.x;
    const int wave = tid >> 6, lane = tid & 63;
    const int l15 = lane & 15, l4 = lane >> 4;
    const int di = tid >> 3, np = tid & 7;     // inner-loop mapping
    const int lr = tid >> 2, lc = tid & 3;     // stage/epilogue mapping
    const bool lead = (np == 0);

    // A constants pre-scaled by log2(e) so exp2 needs no extra mul
    const float A0L = -expf(Al[(d0 + di) * 16 + np]) * 1.4426950408889634f;
    const float A1L = -expf(Al[(d0 + di) * 16 + np + 8]) * 1.4426950408889634f;

    // dt MFMA B-fragments: rows = the block's 32 channels (two 16-ch halves)
    const short8 dtwf0 = *(const short8*)&dtw[(size_t)(d0 + l15) * 32 + l4 * 8];
    const short8 dtwf1 = *(const short8*)&dtw[(size_t)(d0 + 16 + l15) * 32 + l4 * 8];
    const float dtb0 = dtb[d0 + l15], dtb1 = dtb[d0 + 16 + l15];

    float dpv[8];
#pragma unroll
    for (int i = 0; i < 8; ++i) dpv[i] = Dpp[d0 + lc * 8 + i];

    ushort4 pxi0, pxi1;
    float4 pB, pC;
    short8 pA;
    auto issue_loads = [&](int c) {
        const size_t r = (size_t)b * LSEQ + c * 64 + lr;
        pxi0 = *(const ushort4*)&xiy[r * 1024 + d0 + lc * 8];
        pxi1 = *(const ushort4*)&xiy[r * 1024 + d0 + lc * 8 + 4];
        pB   = *(const float4*)&dbl[r * 64 + 32 + lc * 4];
        pC   = *(const float4*)&dbl[r * 64 + 48 + lc * 4];
        // dt MFMA A-fragment: rows = this wave's 16 timesteps of the chunk
        pA   = *(const short8*)&dblh[(size_t)(b * LSEQ + c * 64 + wave * 16 + l15) * 32 + l4 * 8];
    };
    issue_loads(0);

    float h0 = 0.0f, h1 = 0.0f;
    for (int c = 0; c < LSEQ / 64; ++c) {
        const int t0 = c * 64;
        const int buf = c & 1;
        // ---- stage xi (f32, [t][ch], b128) and B/C pairs ----
        {
            float4 xa, xb;
            xa.x = bf2f(pxi0.x); xa.y = bf2f(pxi0.y); xa.z = bf2f(pxi0.z); xa.w = bf2f(pxi0.w);
            xb.x = bf2f(pxi1.x); xb.y = bf2f(pxi1.y); xb.z = bf2f(pxi1.z); xb.w = bf2f(pxi1.w);
            *(float4*)&sxi[buf][lr][lc * 8]     = xa;
            *(float4*)&sxi[buf][lr][lc * 8 + 4] = xb;
        }
        {
            const float bv[4] = {pB.x, pB.y, pB.z, pB.w};
            const float cv[4] = {pC.x, pC.y, pC.z, pC.w};
#pragma unroll
            for (int i = 0; i < 4; ++i) {
                const int n = lc * 4 + i;
                sB2[n & 7][lr * 2 + (n >> 3)] = bv[i];
                sC2[n & 7][lr * 2 + (n >> 3)] = cv[i];
            }
        }
        __syncthreads();
        // ---- dt phase: MFMA -> softplus -> sdt, and dtx = dt*xi -> sdtx ----
        {
            f32x4 z4 = {0.f, 0.f, 0.f, 0.f};
            f32x4 dacc0 = __builtin_amdgcn_mfma_f32_16x16x32_bf16(pA, dtwf0, z4, 0, 0, 0);
            f32x4 dacc1 = __builtin_amdgcn_mfma_f32_16x16x32_bf16(pA, dtwf1, z4, 0, 0, 0);
            const int tq = wave * 16 + l4 * 4;
            float4 xi0, xi1;
            xi0.x = sxi[buf][tq + 0][l15];      xi0.y = sxi[buf][tq + 1][l15];
            xi0.z = sxi[buf][tq + 2][l15];      xi0.w = sxi[buf][tq + 3][l15];
            xi1.x = sxi[buf][tq + 0][16 + l15]; xi1.y = sxi[buf][tq + 1][16 + l15];
            xi1.z = sxi[buf][tq + 2][16 + l15]; xi1.w = sxi[buf][tq + 3][16 + l15];
            float4 dv0, dv1, dx0, dx1;
            dv0.x = softplus_f(dacc0[0] + dtb0); dv0.y = softplus_f(dacc0[1] + dtb0);
            dv0.z = softplus_f(dacc0[2] + dtb0); dv0.w = softplus_f(dacc0[3] + dtb0);
            dv1.x = softplus_f(dacc1[0] + dtb1); dv1.y = softplus_f(dacc1[1] + dtb1);
            dv1.z = softplus_f(dacc1[2] + dtb1); dv1.w = softplus_f(dacc1[3] + dtb1);
            dx0.x = dv0.x * xi0.x; dx0.y = dv0.y * xi0.y;
            dx0.z = dv0.z * xi0.z; dx0.w = dv0.w * xi0.w;
            dx1.x = dv1.x * xi1.x; dx1.y = dv1.y * xi1.y;
            dx1.z = dv1.z * xi1.z; dx1.w = dv1.w * xi1.w;
            *(float4*)&sdt[l15][tq]       = dv0;
            *(float4*)&sdt[16 + l15][tq]  = dv1;
            *(float4*)&sdtx[l15][tq]      = dx0;
            *(float4*)&sdtx[16 + l15][tq] = dx1;
        }
        if (c + 1 < LSEQ / 64) issue_loads(c + 1);
        ushort4 pz0, pz1;
        {
            const int tz = dir ? (LSEQ - 1 - (t0 + lr)) : (t0 + lr);
            pz0 = *(const ushort4*)&zz[((size_t)b * LSEQ + tz) * 2048 + 1024 + d0 + lc * 8];
            pz1 = *(const ushort4*)&zz[((size_t)b * LSEQ + tz) * 2048 + 1024 + d0 + lc * 8 + 4];
        }
        __syncthreads();
        // ---- inner scan: 64 timesteps, 2 states per thread ----
#pragma unroll 4
        for (int tt = 0; tt < 64; tt += 4) {
            const float4 d4 = *(const float4*)&sdt[di][tt];
            const float4 u4 = *(const float4*)&sdtx[di][tt];
            const float4 bA = *(const float4*)&sB2[np][tt * 2];
            const float4 bB = *(const float4*)&sB2[np][tt * 2 + 4];
            const float4 cA = *(const float4*)&sC2[np][tt * 2];
            const float4 cB = *(const float4*)&sC2[np][tt * 2 + 4];
            float4 ppv;
            h0 = fmaf(EXP2F(d4.x * A0L), h0, u4.x * bA.x);
            h1 = fmaf(EXP2F(d4.x * A1L), h1, u4.x * bA.y);
            ppv.x = row_sum8(fmaf(h1, cA.y, h0 * cA.x));
            h0 = fmaf(EXP2F(d4.y * A0L), h0, u4.y * bA.z);
            h1 = fmaf(EXP2F(d4.y * A1L), h1, u4.y * bA.w);
            ppv.y = row_sum8(fmaf(h1, cA.w, h0 * cA.z));
            h0 = fmaf(EXP2F(d4.z * A0L), h0, u4.z * bB.x);
            h1 = fmaf(EXP2F(d4.z * A1L), h1, u4.z * bB.y);
            ppv.z = row_sum8(fmaf(h1, cB.y, h0 * cB.x));
            h0 = fmaf(EXP2F(d4.w * A0L), h0, u4.w * bB.z);
            h1 = fmaf(EXP2F(d4.w * A1L), h1, u4.w * bB.w);
            ppv.w = row_sum8(fmaf(h1, cB.w, h0 * cB.z));
            if (lead) *(float4*)&sy[di][tt] = ppv;
        }
        __syncthreads();
        // ---- epilogue: y + xi*Dp, gate by silu(z), store bf16 ----
        {
            const size_t r = (size_t)b * LSEQ + t0 + lr;
            const float4 xa = *(const float4*)&sxi[buf][lr][lc * 8];
            const float4 xb = *(const float4*)&sxi[buf][lr][lc * 8 + 4];
            float yv[8];
#pragma unroll
            for (int i = 0; i < 8; ++i) yv[i] = sy[lc * 8 + i][lr];
            ushort4 s0, s1;
            s0.x = f2bf(fmaf(xa.x, dpv[0], yv[0]) * silu_f(bf2f(pz0.x)));
            s0.y = f2bf(fmaf(xa.y, dpv[1], yv[1]) * silu_f(bf2f(pz0.y)));
            s0.z = f2bf(fmaf(xa.z, dpv[2], yv[2]) * silu_f(bf2f(pz0.z)));
            s0.w = f2bf(fmaf(xa.w, dpv[3], yv[3]) * silu_f(bf2f(pz0.w)));
            s1.x = f2bf(fmaf(xb.x, dpv[4], yv[4]) * silu_f(bf2f(pz1.x)));
            s1.y = f2bf(fmaf(xb.y, dpv[5], yv[5]) * silu_f(bf2f(pz1.y)));
            s1.z = f2bf(fmaf(xb.z, dpv[6], yv[6]) * silu_f(bf2f(pz1.z)));
            s1.w = f2bf(fmaf(xb.w, dpv[7], yv[7]) * silu_f(bf2f(pz1.w)));
            *(ushort4*)&xiy[r * 1024 + d0 + lc * 8] = s0;
            *(ushort4*)&xiy[r * 1024 + d0 + lc * 8 + 4] = s1;
        }
    }
}

// ---------------------------------------------------------------------------
extern "C" void kernel_launch(void* const* d_in, const int* in_sizes, int n_in,
                              void* d_out, int out_size, void* d_ws, size_t ws_size,
                              hipStream_t stream)
{
    const float* x      = (const float*)d_in[0];
    const float* f_in_w = (const float*)d_in[1];
    const float* f_cw   = (const float*)d_in[2];
    const float* f_cb   = (const float*)d_in[3];
    const float* f_xp   = (const float*)d_in[4];
    const float* f_dtw  = (const float*)d_in[5];
    const float* f_dtb  = (const float*)d_in[6];
    const float* f_Al   = (const float*)d_in[7];
    const float* f_Dp   = (const float*)d_in[8];
    const float* f_ow   = (const float*)d_in[9];
    const float* b_in_w = (const float*)d_in[10];
    const float* b_cw   = (const float*)d_in[11];
    const float* b_cb   = (const float*)d_in[12];
    const float* b_xp   = (const float*)d_in[13];
    const float* b_dtw  = (const float*)d_in[14];
    const float* b_dtb  = (const float*)d_in[15];
    const float* b_Al   = (const float*)d_in[16];
    const float* b_Dp   = (const float*)d_in[17];
    const float* b_ow   = (const float*)d_in[18];
    const float* lin_w  = (const float*)d_in[19];
    const float* lin_b  = (const float*)d_in[20];
    float* out = (float*)d_out;

    char* p = (char*)d_ws;
    auto take = [&](size_t bytes) -> char* {
        char* r = p; p += (bytes + 255) & ~(size_t)255; return r;
    };

    // persistent bf16 weights
    unsigned short* wif  = (unsigned short*)take((size_t)2048 * 512 * 2);
    unsigned short* wib  = (unsigned short*)take((size_t)2048 * 512 * 2);
    unsigned short* wxf  = (unsigned short*)take((size_t)64 * 1024 * 2);
    unsigned short* wxb  = (unsigned short*)take((size_t)64 * 1024 * 2);
    unsigned short* wdtf = (unsigned short*)take((size_t)1024 * 32 * 2);
    unsigned short* wdtb = (unsigned short*)take((size_t)1024 * 32 * 2);
    unsigned short* wcmb = (unsigned short*)take((size_t)512 * 2048 * 2);

    const size_t used = (size_t)(p - (char*)d_ws);
    // per-row bytes: xbf 1024 + per dir (xz 4096 + xiy 2048 + dbl 256 + dblh 64)
    const size_t perRow = 1024 + 2 * (4096 + 2048 + 256 + 64);
    int G = 1;
    for (int g = 8; g >= 1; g >>= 1) {
        const size_t need = used + (size_t)g * LSEQ * perRow + 16384;
        if (need <= ws_size || g == 1) { G = g; break; }
    }

    CvtArgs ca;
    ca.s[0] = f_in_w; ca.d[0] = wif;  ca.n[0] = 2048 * 512;
    ca.s[1] = b_in_w; ca.d[1] = wib;  ca.n[1] = 2048 * 512;
    ca.s[2] = f_xp;   ca.d[2] = wxf;  ca.n[2] = 64 * 1024;
    ca.s[3] = b_xp;   ca.d[3] = wxb;  ca.n[3] = 64 * 1024;
    ca.s[4] = f_dtw;  ca.d[4] = wdtf; ca.n[4] = 1024 * 32;
    ca.s[5] = b_dtw;  ca.d[5] = wdtb; ca.n[5] = 1024 * 32;
    cvt_k<<<dim3(128, 6), 256, 0, stream>>>(ca);

    // combined (lin_w @ out_w) weight, bf16, (512 x 2048) — proven r7
    combine_k<<<dim3(4, 128, 2), 256, 0, stream>>>(lin_w, f_ow, b_ow, wcmb);

    char* pg0 = p;
    for (int g0 = 0; g0 < NBATCH; g0 += G) {
        const int Mg = G * LSEQ;
        p = pg0;
        unsigned short* xbf   = (unsigned short*)take((size_t)Mg * 512 * 2);
        unsigned short* xz_f  = (unsigned short*)take((size_t)Mg * 2048 * 2);
        unsigned short* xz_b  = (unsigned short*)take((size_t)Mg * 2048 * 2);
        unsigned short* xiy_f = (unsigned short*)take((size_t)Mg * 1024 * 2);
        unsigned short* xiy_b = (unsigned short*)take((size_t)Mg * 1024 * 2);
        float* dbl_f          = (float*)take((size_t)Mg * 64 * 4);
        float* dbl_b          = (float*)take((size_t)Mg * 64 * 4);
        unsigned short* dblh_f= (unsigned short*)take((size_t)Mg * 32 * 2);
        unsigned short* dblh_b= (unsigned short*)take((size_t)Mg * 32 * 2);

        const float* xg = x + (size_t)g0 * LSEQ * 512;
        float* outg = out + (size_t)g0 * LSEQ * 512;

        cvtx_k<<<dim3(512), 256, 0, stream>>>(xg, xbf, Mg * 512 / 4);

        GemmPair g1 = {};   // in-proj: xz = x @ in_w^T (N=2048), bf16 out
        g1.A[0] = xbf; g1.A[1] = xbf; g1.W[0] = wif; g1.W[1] = wib;
        g1.C[0] = xz_f; g1.C[1] = xz_b;
        gemm_mfma<2,2,1,0,0><<<dim3(Mg/128, 16, 2), 256, 0, stream>>>(g1, 512, 512, 2048, 512);

        conv_silu_k<<<dim3(Mg, 2), 256, 0, stream>>>(xz_f, f_cw, f_cb, xiy_f,
                                                     xz_b, b_cw, b_cb, xiy_b);

        GemmPair g2 = {};   // x-proj: dbl f32 (ldc 64) + bf16 cols<32 (dblh)
        g2.A[0] = xiy_f; g2.A[1] = xiy_b; g2.W[0] = wxf; g2.W[1] = wxb;
        g2.C[0] = dbl_f; g2.C[1] = dbl_b; g2.aux[0] = dblh_f; g2.aux[1] = dblh_b;
        gemm_mfma<4,1,0,0,1><<<dim3(Mg/256, 1, 2), 256, 0, stream>>>(g2, 1024, 1024, 64, 1024);

        ScanPair spp = {};  // scan: 32 ch x 8 state-pairs per block
        spp.dblh[0] = dblh_f; spp.dblh[1] = dblh_b;
        spp.dtw[0] = wdtf;    spp.dtw[1] = wdtb;
        spp.dtb[0] = f_dtb;   spp.dtb[1] = b_dtb;
        spp.xiy[0] = xiy_f;   spp.xiy[1] = xiy_b;
        spp.dbl[0] = dbl_f;   spp.dbl[1] = dbl_b;
        spp.xz[0] = xz_f;     spp.xz[1] = xz_b;
        spp.Al[0] = f_Al;     spp.Al[1] = b_Al;
        spp.Dp[0] = f_Dp;     spp.Dp[1] = b_Dp;
        scan_k<<<dim3(32, G, 2), 256, 0, stream>>>(spp);

        // fused out-proj+final: out = [y_f | rev(y_b)] @ Wcomb^T + lin_b (K=2048)
        GemmPair g5 = {};
        g5.A[0] = xiy_f; g5.A2[0] = xiy_b; g5.W[0] = wcmb;
        g5.bias[0] = lin_b; g5.C[0] = outg;
        gemm_mfma<2,2,0,1024,0><<<dim3(Mg/128, 4, 1), 256, 0, stream>>>(g5, 1024, 2048, 512, 2048);
    }
}